// Round 21
// baseline (111.850 us; speedup 1.0000x reference)
//
#include <hip/hip_runtime.h>

// B=2, T=2048, C=1024, H=16, HD=64, SCALE=0.125
// Pipeline: cvt x->bf16; transpose W->bf16 [N][K]; GEMM1 qkv=x@Wqkv (bf16 out,
// Q cols pre-scaled by SCALE*log2e, V cols written transposed into vT);
// flash attn v14 (warp owns 64 q-rows as two 32-row subtiles A/B SHARING the
// same K/V register fragments -> staging+DS per q-row halves, 16 MFMA32 per
// tile-visit; 4-way kv-split, split K/V vmcnt waits, max3, permlane P
// relayout, O^T accum, 2x tree merge); GEMM2 out = att@Wp + bp.

typedef __attribute__((ext_vector_type(8))) short shortx8;
typedef __attribute__((ext_vector_type(4))) short shortx4;
typedef __attribute__((ext_vector_type(8))) unsigned short ushortx8;
typedef __attribute__((ext_vector_type(4))) float f32x4;
typedef __attribute__((ext_vector_type(16))) float f32x16;
typedef __attribute__((ext_vector_type(2))) unsigned uintx2;

#define MFMA16(a, b, c) __builtin_amdgcn_mfma_f32_16x16x32_bf16((a), (b), (c), 0, 0, 0)
#define MFMA32(a, b, c) __builtin_amdgcn_mfma_f32_32x32x16_bf16((a), (b), (c), 0, 0, 0)

// SCALE * log2(e): softmax done in exp2 domain; folded into Q at GEMM1 epilogue
#define SC_L2E 0.18033688011112042f

__device__ __forceinline__ unsigned short f2bf(float f) {
  union { float f; unsigned u; } v; v.f = f;
  unsigned r = v.u + 0x7fffu + ((v.u >> 16) & 1u);  // RNE; inputs finite
  return (unsigned short)(r >> 16);
}

__device__ __forceinline__ unsigned cvtpk(float a, float b) {
  unsigned r;
  asm("v_cvt_pk_bf16_f32 %0, %1, %2" : "=v"(r) : "v"(a), "v"(b));
  return r;
}

__device__ __forceinline__ float fexp2(float x) {
#if __has_builtin(__builtin_amdgcn_exp2f)
  return __builtin_amdgcn_exp2f(x);
#else
  return exp2f(x);
#endif
}

// v_permlane32_swap_b32: r[0] = {lo: a.lo, hi: b.lo}, r[1] = {lo: a.hi, hi: b.hi}
__device__ __forceinline__ uintx2 plswap(unsigned a, unsigned b) {
#if __has_builtin(__builtin_amdgcn_permlane32_swap)
  return __builtin_amdgcn_permlane32_swap(a, b, false, false);
#else
  asm volatile("v_permlane32_swap_b32 %0, %1" : "+v"(a), "+v"(b));
  uintx2 r; r[0] = a; r[1] = b; return r;
#endif
}

__device__ __forceinline__ float partner32(float x, int hi) {
  unsigned u = __builtin_bit_cast(unsigned, x);
  uintx2 r = plswap(u, u);
  return __builtin_bit_cast(float, hi ? r[0] : r[1]);
}

__device__ __forceinline__ float max3(float a, float b, float c) {
  return fmaxf(fmaxf(a, b), c);  // clang fuses to v_max3_f32
}

__device__ __forceinline__ void gload16(const void* g, void* l) {
  __builtin_amdgcn_global_load_lds(
      (const __attribute__((address_space(1))) void*)g,
      (__attribute__((address_space(3))) void*)l, 16, 0, 0);
}

// ---------------- conversions ----------------
__global__ __launch_bounds__(256) void cvt_x(const float* __restrict__ x,
                                             unsigned short* __restrict__ xb, int n4) {
  int i = blockIdx.x * 256 + threadIdx.x;
  if (i < n4) {
    float4 v = ((const float4*)x)[i];
    unsigned short* o = xb + (size_t)i * 4;
    o[0] = f2bf(v.x); o[1] = f2bf(v.y); o[2] = f2bf(v.z); o[3] = f2bf(v.w);
  }
}

// 4x W [1024][1024] f32 -> WT [1024][1024] bf16 (WT[n][k] = W[k][n]); z picks matrix
__global__ __launch_bounds__(256) void transpose_w4(
    const float* __restrict__ Wq, const float* __restrict__ Wk,
    const float* __restrict__ Wv, const float* __restrict__ Wp,
    unsigned short* __restrict__ wqkvT, unsigned short* __restrict__ wpT) {
  __shared__ float tile[32][33];
  const int zi = blockIdx.z;
  const float* src = (zi == 0) ? Wq : (zi == 1) ? Wk : (zi == 2) ? Wv : Wp;
  unsigned short* dst = (zi == 3) ? wpT : wqkvT + (size_t)zi * 1048576;
  const int bx = blockIdx.x * 32, by = blockIdx.y * 32;
  const int tx = threadIdx.x & 31, ty = threadIdx.x >> 5;  // 32 x 8
  #pragma unroll
  for (int i = 0; i < 32; i += 8)
    tile[ty + i][tx] = src[(size_t)(by + ty + i) * 1024 + bx + tx];
  __syncthreads();
  #pragma unroll
  for (int i = 0; i < 32; i += 8)
    dst[(size_t)(bx + ty + i) * 1024 + by + tx] = f2bf(tile[tx][ty + i]);
}

// ---------------- GEMM: C[M,N] = A[M,K] @ BT[N,K]^T ----------------
// 3 LDS buffers, depth-1 staging, ONE barrier per K-step (reuse distance 3;
// lgkmcnt(0) before loop-back). vmcnt(4) leaves next-tile loads in flight
// across the barrier. qscale applied to bf16 cols < scale_cols; cols >= 2048
// (V part) written TRANSPOSED into vTo when vTo != null.
__global__ __launch_bounds__(256) void gemm_bt(
    const unsigned short* __restrict__ A, const unsigned short* __restrict__ BT,
    unsigned short* __restrict__ Cb, float* __restrict__ Cf,
    const float* __restrict__ bias, int M, int N, int K,
    float qscale, int scale_cols, unsigned short* __restrict__ vTo) {
  __shared__ unsigned short As[3][4096];
  __shared__ unsigned short Bs[3][4096];
  const int tid = threadIdx.x;
  const int lane = tid & 63, w = tid >> 6;
  const int wr = w >> 1, wc = w & 1;
  const int brow = blockIdx.y << 7, bcol = blockIdx.x << 7;

  f32x4 z = {0.f, 0.f, 0.f, 0.f};
  f32x4 acc[4][4];
  #pragma unroll
  for (int m = 0; m < 4; ++m)
    #pragma unroll
    for (int n = 0; n < 4; ++n) acc[m][n] = z;

  const int srow = tid >> 2;
  const int scol = (tid & 3) << 3;
  const unsigned short* Ap = A + (size_t)(brow + srow) * K + scol;
  const unsigned short* Bp = BT + (size_t)(bcol + srow) * K + scol;
  const size_t rowK64 = (size_t)64 * K;

  #define GSTAGE(k0_, bi_)                                   \
    do {                                                     \
      unsigned short* AsW = &As[bi_][w * 512];               \
      unsigned short* BsW = &Bs[bi_][w * 512];               \
      gload16(Ap + (k0_), AsW);                              \
      gload16(Ap + rowK64 + (k0_), AsW + 2048);              \
      gload16(Bp + (k0_), BsW);                              \
      gload16(Bp + rowK64 + (k0_), BsW + 2048);              \
    } while (0)

  const int koff = (lane >> 4) << 3;
  const int ar = (wr << 6) + (lane & 15);
  const int br = (wc << 6) + (lane & 15);
  const int nt = K >> 5;
  int cur = 0;
  GSTAGE(0, 0);
  for (int t = 0; t < nt; ++t) {
    const int nxt = (cur + 1 == 3) ? 0 : cur + 1;
    if (t + 1 < nt) {
      GSTAGE((size_t)(t + 1) << 5, nxt);
      asm volatile("s_waitcnt vmcnt(4)" ::: "memory");  // tile t landed; t+1 in flight
    } else {
      asm volatile("s_waitcnt vmcnt(0)" ::: "memory");
    }
    __builtin_amdgcn_sched_barrier(0);
    __builtin_amdgcn_s_barrier();
    __builtin_amdgcn_sched_barrier(0);
    shortx8 af[4], bf[4];
    #pragma unroll
    for (int m = 0; m < 4; ++m) af[m] = *(const shortx8*)&As[cur][(ar + m * 16) * 32 + koff];
    #pragma unroll
    for (int n = 0; n < 4; ++n) bf[n] = *(const shortx8*)&Bs[cur][(br + n * 16) * 32 + koff];
    #pragma unroll
    for (int m = 0; m < 4; ++m)
      #pragma unroll
      for (int n = 0; n < 4; ++n) acc[m][n] = MFMA16(af[m], bf[n], acc[m][n]);
    asm volatile("s_waitcnt lgkmcnt(0)" ::: "memory");  // reads retired before next barrier
    __builtin_amdgcn_sched_barrier(0);
    cur = nxt;
  }
  #undef GSTAGE

  const int r0 = (lane >> 4) << 2;
  const int c0 = lane & 15;
  if (Cb) {
    if (vTo && bcol >= 2048) {
      #pragma unroll
      for (int m = 0; m < 4; ++m)
        #pragma unroll
        for (int n = 0; n < 4; ++n) {
          const int dp = bcol - 2048 + (wc << 6) + n * 16 + c0;
          const size_t rowb = brow + (wr << 6) + m * 16 + r0;
          uint2 u;
          u.x = cvtpk(acc[m][n][0], acc[m][n][1]);
          u.y = cvtpk(acc[m][n][2], acc[m][n][3]);
          *(uint2*)&vTo[(size_t)dp * 4096 + rowb] = u;
        }
    } else {
      #pragma unroll
      for (int m = 0; m < 4; ++m)
        #pragma unroll
        for (int n = 0; n < 4; ++n)
          #pragma unroll
          for (int j = 0; j < 4; ++j) {
            const size_t row = brow + (wr << 6) + m * 16 + r0 + j;
            const size_t col = bcol + (wc << 6) + n * 16 + c0;
            float v = acc[m][n][j];
            if ((int)col < scale_cols) v *= qscale;
            Cb[row * N + col] = f2bf(v);
          }
    }
  } else {
    #pragma unroll
    for (int m = 0; m < 4; ++m)
      #pragma unroll
      for (int n = 0; n < 4; ++n)
        #pragma unroll
        for (int j = 0; j < 4; ++j) {
          const size_t row = brow + (wr << 6) + m * 16 + r0 + j;
          const size_t col = bcol + (wc << 6) + n * 16 + c0;
          Cf[row * N + col] = acc[m][n][j] + bias[col];
        }
  }
}

// ---------------- flash attention v14 (64 q-rows/warp, shared K/V frags) ----------------
// Block = 4 INDEPENDENT warps over the SAME 64 q-rows (subtiles A: +0..31,
// B: +32..63, one q-col per lane each); warp p does kv tiles t===p (mod 4),
// KVBLK=32, tmax = 2*qb+1. Single 8KB LDS buffer per warp; K loads then V
// loads (vmcnt(4) releases K early). Per visit: kf -> QK_A -> softmaxA ->
// QK_B (kf dead) -> vf -> restage -> softmaxB -> PV_A -> PV_B (16 MFMA32
// per visit vs 8 loads). Defer-max, max3 tree, permlane exchange, O^T accum.
// End: tree merge of 4 partial states, run twice (A then B).

__global__ __launch_bounds__(256, 3) void attn_fwd(
    const unsigned short* __restrict__ qkv, const unsigned short* __restrict__ vT,
    unsigned short* __restrict__ att) {
  __shared__ unsigned short sh[4][4096];  // [warp][ K[32kv][64d] | V^T[64d][32kv] ]

  const int tid = threadIdx.x;
  const int lane = tid & 63;
  const int p = tid >> 6;                  // warp id = kv residue (mod 4)
  const int stream = blockIdx.x;           // (h,b)
  const int h = stream & 15, b = stream >> 4;
  const int qb = 31 - (int)blockIdx.y;     // 64-row q block, descending work
  const int ql = lane & 31;
  const int hi = lane >> 5;
  const int qA = qb * 64 + ql;
  const int qB = qA + 32;

  // Q^T B-operands: qf[kc] = Q[q][16kc + 8hi + e], pre-scaled by SC_L2E
  shortx8 qfA[4], qfB[4];
  {
    const unsigned short* qpA = qkv + ((size_t)(b * 2048 + qA)) * 3072 + h * 64 + 8 * hi;
    const unsigned short* qpB = qkv + ((size_t)(b * 2048 + qB)) * 3072 + h * 64 + 8 * hi;
    #pragma unroll
    for (int kc = 0; kc < 4; ++kc) {
      qfA[kc] = *(const shortx8*)(qpA + 16 * kc);
      qfB[kc] = *(const shortx8*)(qpB + 16 * kc);
    }
  }

  f32x16 z16;
  #pragma unroll
  for (int i = 0; i < 16; ++i) z16[i] = 0.f;
  f32x16 accA0 = z16, accA1 = z16;  // O^T[d = 32dh + crow(r,hi)][qA]
  f32x16 accB0 = z16, accB1 = z16;
  float mA = -__builtin_inff(), lA = 0.f;
  float mB = -__builtin_inff(), lB = 0.f;

  // staging source bases (pre-swizzled): K row r -> chunk XOR S8(r), V -> S4(r)
  const unsigned short* kb[4];
  const unsigned short* vb[4];
  #pragma unroll
  for (int i = 0; i < 4; ++i) {
    const int krow = 8 * i + (lane >> 3);
    const int kcl = (lane & 7) ^ (((krow >> 1) ^ (krow >> 4)) & 7);
    kb[i] = qkv + ((size_t)(b * 2048 + krow)) * 3072 + 1024 + h * 64 + 8 * kcl;
    const int vrow = 16 * i + (lane >> 2);
    const int vcl = (lane & 3) ^ (((vrow >> 1) ^ (vrow >> 3)) & 3);
    vb[i] = vT + ((size_t)(h * 64 + vrow)) * 4096 + b * 2048 + 8 * vcl;
  }
  const int rs8 = ((ql >> 1) ^ (ql >> 4)) & 7;
  const int rs4 = ((ql >> 1) ^ (ql >> 3)) & 3;

  unsigned short* Kl = &sh[p][0];
  unsigned short* Vl = &sh[p][2048];

  // K loads first, V loads second: vmcnt(4) == K landed
  #define STAGE(t_)                                                        \
    do {                                                                   \
      _Pragma("unroll")                                                    \
      for (int i = 0; i < 4; ++i)                                          \
        gload16(kb[i] + (size_t)(t_) * 32 * 3072, Kl + i * 512);           \
      _Pragma("unroll")                                                    \
      for (int i = 0; i < 4; ++i)                                          \
        gload16(vb[i] + (t_) * 32, Vl + i * 512);                          \
    } while (0)

  // softmax over s_ (16 regs + partner), defer-max rescale of (A0_,A1_),
  // result packed to wv_ (8 u32 of bf16 pairs)
  #define SMAX(s_, mr_, lr_, A0_, A1_, wv_)                                \
    do {                                                                   \
      float t0 = max3(s_[0], s_[1], s_[2]);                                \
      float t1 = max3(s_[3], s_[4], s_[5]);                                \
      float t2 = max3(s_[6], s_[7], s_[8]);                                \
      float t3 = max3(s_[9], s_[10], s_[11]);                              \
      float t4 = max3(s_[12], s_[13], s_[14]);                             \
      float mx = fmaxf(max3(t0, t1, t2), max3(t3, t4, s_[15]));            \
      mx = fmaxf(mx, partner32(mx, hi));                                   \
      if (!__all(mx <= (mr_) + 8.0f)) {                                    \
        const float nm = fmaxf(mr_, mx);                                   \
        const float alpha = fexp2((mr_) - nm);                             \
        (lr_) *= alpha;                                                    \
        _Pragma("unroll")                                                  \
        for (int r = 0; r < 16; ++r) { A0_[r] *= alpha; A1_[r] *= alpha; } \
        (mr_) = nm;                                                        \
      }                                                                    \
      _Pragma("unroll")                                                    \
      for (int r = 0; r < 16; ++r) s_[r] = fexp2(s_[r] - (mr_));           \
      float a8[8], a4[4];                                                  \
      _Pragma("unroll")                                                    \
      for (int i = 0; i < 8; ++i) a8[i] = s_[2 * i] + s_[2 * i + 1];       \
      _Pragma("unroll")                                                    \
      for (int i = 0; i < 4; ++i) a4[i] = a8[2 * i] + a8[2 * i + 1];       \
      float rsum = (a4[0] + a4[1]) + (a4[2] + a4[3]);                      \
      rsum += partner32(rsum, hi);                                         \
      (lr_) += rsum;                                                       \
      _Pragma("unroll")                                                    \
      for (int i = 0; i < 8; ++i) wv_[i] = cvtpk(s_[2 * i], s_[2 * i + 1]);\
    } while (0)

  #define PV(wv_, A0_, A1_)                                                \
    do {                                                                   \
      _Pragma("unroll")                                                    \
      for (int ss = 0; ss < 2; ++ss) {                                     \
        uintx2 r02 = plswap(wv_[4 * ss], wv_[4 * ss + 2]);                 \
        uintx2 r13 = plswap(wv_[4 * ss + 1], wv_[4 * ss + 3]);             \
        union { unsigned u[4]; shortx8 s8; } pb;                           \
        pb.u[0] = r02[0];                                                  \
        pb.u[1] = r13[0];                                                  \
        pb.u[2] = r02[1];                                                  \
        pb.u[3] = r13[1];                                                  \
        A0_ = MFMA32(vf[0][ss], pb.s8, A0_);                               \
        A1_ = MFMA32(vf[1][ss], pb.s8, A1_);                               \
      }                                                                    \
    } while (0)

  const int tmax = 2 * qb + 1;
  if (p <= tmax) STAGE(p);
  for (int t = p; t <= tmax; t += 4) {
    const bool actA = (t <= 2 * qb);
    asm volatile("s_waitcnt vmcnt(4)" ::: "memory");  // K tile landed
    __builtin_amdgcn_sched_barrier(0);
    shortx8 kf[4];
    #pragma unroll
    for (int kc = 0; kc < 4; ++kc)
      kf[kc] = *(const shortx8*)&Kl[ql * 64 + 8 * ((2 * kc + hi) ^ rs8)];
    asm volatile("s_waitcnt lgkmcnt(0)" ::: "memory");
    __builtin_amdgcn_sched_barrier(0);

    unsigned wvA[8];
    if (actA) {
      __builtin_amdgcn_s_setprio(1);
      f32x16 sA = z16;
      #pragma unroll
      for (int kc = 0; kc < 4; ++kc) sA = MFMA32(kf[kc], qfA[kc], sA);
      __builtin_amdgcn_s_setprio(0);
      if (t == 2 * qb) {  // A's diagonal tile
        #pragma unroll
        for (int r = 0; r < 16; ++r) {
          const int kvl = (r & 3) + 8 * (r >> 2) + 4 * hi;
          if (kvl > ql) sA[r] = -__builtin_inff();
        }
      }
      SMAX(sA, mA, lA, accA0, accA1, wvA);
    }

    // QK_B (kf dead afterwards)
    __builtin_amdgcn_s_setprio(1);
    f32x16 sB = z16;
    #pragma unroll
    for (int kc = 0; kc < 4; ++kc) sB = MFMA32(kf[kc], qfB[kc], sB);
    __builtin_amdgcn_s_setprio(0);

    asm volatile("s_waitcnt vmcnt(0)" ::: "memory");  // V tile landed
    __builtin_amdgcn_sched_barrier(0);
    shortx8 vf[2][2];
    #pragma unroll
    for (int dh = 0; dh < 2; ++dh)
      #pragma unroll
      for (int ks = 0; ks < 2; ++ks)
        vf[dh][ks] = *(const shortx8*)&Vl[(32 * dh + ql) * 32 + 8 * ((2 * ks + hi) ^ rs4)];
    asm volatile("s_waitcnt lgkmcnt(0)" ::: "memory");  // frags in regs; buffer dead
    __builtin_amdgcn_sched_barrier(0);

    if (t + 4 <= tmax) STAGE(t + 4);  // restage same buffer; compute hides return

    if (t == tmax) {  // B's diagonal tile (t == 2qb+1)
      #pragma unroll
      for (int r = 0; r < 16; ++r) {
        const int kvl = (r & 3) + 8 * (r >> 2) + 4 * hi;
        if (kvl > ql) sB[r] = -__builtin_inff();
      }
    }
    unsigned wvB[8];
    SMAX(sB, mB, lB, accB0, accB1, wvB);

    __builtin_amdgcn_s_setprio(1);
    if (actA) PV(wvA, accA0, accA1);
    PV(wvB, accB0, accB1);
    __builtin_amdgcn_s_setprio(0);
  }
  #undef STAGE

  // ---- tree merge of 4 kv-partial states, run per subtile ----
  float* fb = (float*)&sh[0][0];
  #define DUMP(slot_, A0_, A1_, mr_, lr_)                                      \
    do {                                                                       \
      float* ob = fb + (slot_) * 2048;                                         \
      _Pragma("unroll")                                                        \
      for (int rg = 0; rg < 4; ++rg) {                                         \
        f32x4 v0 = {A0_[4 * rg], A0_[4 * rg + 1], A0_[4 * rg + 2], A0_[4 * rg + 3]}; \
        f32x4 v1 = {A1_[4 * rg], A1_[4 * rg + 1], A1_[4 * rg + 2], A1_[4 * rg + 3]}; \
        *(f32x4*)&ob[(rg * 64 + lane) * 4] = v0;                               \
        *(f32x4*)&ob[((4 + rg) * 64 + lane) * 4] = v1;                         \
      }                                                                        \
      fb[4096 + (slot_) * 128 + lane] = (mr_);                                 \
      fb[4096 + (slot_) * 128 + 64 + lane] = (lr_);                            \
    } while (0)
  #define MERGE(slot_, A0_, A1_, mr_, lr_)                                     \
    do {                                                                       \
      const float m2 = fb[4096 + (slot_) * 128 + lane];                        \
      const float l2 = fb[4096 + (slot_) * 128 + 64 + lane];                   \
      if (m2 != -__builtin_inff()) {                                           \
        float* ob = fb + (slot_) * 2048;                                       \
        const float mf = fmaxf(mr_, m2);                                       \
        const float a1 = fexp2((mr_) - mf);                                    \
        const float a2 = fexp2(m2 - mf);                                       \
        _Pragma("unroll")                                                      \
        for (int rg = 0; rg < 4; ++rg) {                                       \
          f32x4 p0 = *(const f32x4*)&ob[(rg * 64 + lane) * 4];                 \
          f32x4 p1 = *(const f32x4*)&ob[((4 + rg) * 64 + lane) * 4];           \
          _Pragma("unroll")                                                    \
          for (int j = 0; j < 4; ++j) {                                        \
            A0_[4 * rg + j] = A0_[4 * rg + j] * a1 + p0[j] * a2;               \
            A1_[4 * rg + j] = A1_[4 * rg + j] * a1 + p1[j] * a2;               \
          }                                                                    \
        }                                                                      \
        (lr_) = (lr_) * a1 + l2 * a2;                                          \
        (mr_) = mf;                                                            \
      }                                                                        \
    } while (0)
  #define TREE(A0_, A1_, mr_, lr_, qrow_)                                      \
    do {                                                                       \
      __syncthreads();                                                         \
      if (p == 1) DUMP(0, A0_, A1_, mr_, lr_);                                 \
      if (p == 3) DUMP(1, A0_, A1_, mr_, lr_);                                 \
      __syncthreads();                                                         \
      if (p == 0) MERGE(0, A0_, A1_, mr_, lr_);                                \
      if (p == 2) MERGE(1, A0_, A1_, mr_, lr_);                                \
      __syncthreads();                                                         \
      if (p == 2) DUMP(0, A0_, A1_, mr_, lr_);                                 \
      __syncthreads();                                                         \
      if (p == 0) {                                                            \
        MERGE(0, A0_, A1_, mr_, lr_);                                          \
        const float inv = 1.f / (lr_);                                         \
        unsigned short* op = att + ((size_t)(b * 2048 + (qrow_))) * 1024 + h * 64; \
        _Pragma("unroll")                                                      \
        for (int rq = 0; rq < 4; ++rq) {                                       \
          shortx4 o0, o1;                                                      \
          _Pragma("unroll")                                                    \
          for (int j = 0; j < 4; ++j) {                                        \
            o0[j] = (short)f2bf(A0_[4 * rq + j] * inv);                        \
            o1[j] = (short)f2bf(A1_[4 * rq + j] * inv);                        \
          }                                                                    \
          *(shortx4*)&op[8 * rq + 4 * hi] = o0;                                \
          *(shortx4*)&op[32 + 8 * rq + 4 * hi] = o1;                           \
        }                                                                      \
      }                                                                        \
    } while (0)

  TREE(accA0, accA1, mA, lA, qA);
  TREE(accB0, accB1, mB, lB, qB);
  #undef DUMP
  #undef MERGE
  #undef TREE
  #undef SMAX
  #undef PV
}

// ---------------- launch ----------------
extern "C" void kernel_launch(void* const* d_in, const int* in_sizes, int n_in,
                              void* d_out, int out_size, void* d_ws, size_t ws_size,
                              hipStream_t stream) {
  const float* x  = (const float*)d_in[0];
  const float* Wq = (const float*)d_in[1];
  const float* Wk = (const float*)d_in[2];
  const float* Wv = (const float*)d_in[3];
  const float* Wp = (const float*)d_in[4];
  const float* bp = (const float*)d_in[5];

  char* ws = (char*)d_ws;
  unsigned short* xb    = (unsigned short*)(ws);                        //  8 MB [4096][1024]
  unsigned short* wqkvT = (unsigned short*)(ws + (size_t)8  * 1048576); //  6 MB [3072][1024]
  unsigned short* wpT   = (unsigned short*)(ws + (size_t)14 * 1048576); //  2 MB [1024][1024]
  unsigned short* qkv   = (unsigned short*)(ws + (size_t)16 * 1048576); // 24 MB [4096][3072]
  unsigned short* vT    = (unsigned short*)(ws + (size_t)40 * 1048576); //  8 MB [1024][4096]
  unsigned short* att   = (unsigned short*)(ws + (size_t)48 * 1048576); //  8 MB [4096][1024]

  cvt_x<<<dim3(4096), dim3(256), 0, stream>>>(x, xb, 1048576);
  transpose_w4<<<dim3(32, 32, 4), dim3(256), 0, stream>>>(Wq, Wk, Wv, Wp, wqkvT, wpT);
  gemm_bt<<<dim3(24, 32), dim3(256), 0, stream>>>(xb, wqkvT, qkv, nullptr, nullptr,
                                                  4096, 3072, 1024, SC_L2E, 1024, vT);
  attn_fwd<<<dim3(32, 32), dim3(256), 0, stream>>>(qkv, vT, att);
  gemm_bt<<<dim3(8, 32), dim3(256), 0, stream>>>(att, wpT, nullptr, (float*)d_out, bp,
                                                 4096, 1024, 1024, 0.f, 0, nullptr);
}

// Round 22
// 107.640 us; speedup vs baseline: 1.0391x; 1.0391x over previous
//
#include <hip/hip_runtime.h>

// B=2, T=2048, C=1024, H=16, HD=64, SCALE=0.125
// Pipeline: cvt x->bf16; transpose W->bf16 [N][K]; GEMM1 qkv=x@Wqkv (bf16 out,
// Q cols pre-scaled by SCALE*log2e, V cols written transposed into vT);
// flash attn v13 (4-way kv-split, split K/V vmcnt waits, max3 reduction,
// permlane P relayout, O^T accum, tree merge); GEMM2 out = att@Wp + bp.
// Final: round-20 configuration (best measured 107.8 us). Round-21's
// 64-q-row/warp variant spilled (WRITE 8->20MB scratch traffic).

typedef __attribute__((ext_vector_type(8))) short shortx8;
typedef __attribute__((ext_vector_type(4))) short shortx4;
typedef __attribute__((ext_vector_type(8))) unsigned short ushortx8;
typedef __attribute__((ext_vector_type(4))) float f32x4;
typedef __attribute__((ext_vector_type(16))) float f32x16;
typedef __attribute__((ext_vector_type(2))) unsigned uintx2;

#define MFMA16(a, b, c) __builtin_amdgcn_mfma_f32_16x16x32_bf16((a), (b), (c), 0, 0, 0)
#define MFMA32(a, b, c) __builtin_amdgcn_mfma_f32_32x32x16_bf16((a), (b), (c), 0, 0, 0)

// SCALE * log2(e): softmax done in exp2 domain; folded into Q at GEMM1 epilogue
#define SC_L2E 0.18033688011112042f

__device__ __forceinline__ unsigned short f2bf(float f) {
  union { float f; unsigned u; } v; v.f = f;
  unsigned r = v.u + 0x7fffu + ((v.u >> 16) & 1u);  // RNE; inputs finite
  return (unsigned short)(r >> 16);
}

__device__ __forceinline__ unsigned cvtpk(float a, float b) {
  unsigned r;
  asm("v_cvt_pk_bf16_f32 %0, %1, %2" : "=v"(r) : "v"(a), "v"(b));
  return r;
}

__device__ __forceinline__ float fexp2(float x) {
#if __has_builtin(__builtin_amdgcn_exp2f)
  return __builtin_amdgcn_exp2f(x);
#else
  return exp2f(x);
#endif
}

// v_permlane32_swap_b32: r[0] = {lo: a.lo, hi: b.lo}, r[1] = {lo: a.hi, hi: b.hi}
__device__ __forceinline__ uintx2 plswap(unsigned a, unsigned b) {
#if __has_builtin(__builtin_amdgcn_permlane32_swap)
  return __builtin_amdgcn_permlane32_swap(a, b, false, false);
#else
  asm volatile("v_permlane32_swap_b32 %0, %1" : "+v"(a), "+v"(b));
  uintx2 r; r[0] = a; r[1] = b; return r;
#endif
}

__device__ __forceinline__ float partner32(float x, int hi) {
  unsigned u = __builtin_bit_cast(unsigned, x);
  uintx2 r = plswap(u, u);
  return __builtin_bit_cast(float, hi ? r[0] : r[1]);
}

__device__ __forceinline__ float max3(float a, float b, float c) {
  return fmaxf(fmaxf(a, b), c);  // clang fuses to v_max3_f32
}

__device__ __forceinline__ void gload16(const void* g, void* l) {
  __builtin_amdgcn_global_load_lds(
      (const __attribute__((address_space(1))) void*)g,
      (__attribute__((address_space(3))) void*)l, 16, 0, 0);
}

// ---------------- conversions ----------------
__global__ __launch_bounds__(256) void cvt_x(const float* __restrict__ x,
                                             unsigned short* __restrict__ xb, int n4) {
  int i = blockIdx.x * 256 + threadIdx.x;
  if (i < n4) {
    float4 v = ((const float4*)x)[i];
    unsigned short* o = xb + (size_t)i * 4;
    o[0] = f2bf(v.x); o[1] = f2bf(v.y); o[2] = f2bf(v.z); o[3] = f2bf(v.w);
  }
}

// 4x W [1024][1024] f32 -> WT [1024][1024] bf16 (WT[n][k] = W[k][n]); z picks matrix
__global__ __launch_bounds__(256) void transpose_w4(
    const float* __restrict__ Wq, const float* __restrict__ Wk,
    const float* __restrict__ Wv, const float* __restrict__ Wp,
    unsigned short* __restrict__ wqkvT, unsigned short* __restrict__ wpT) {
  __shared__ float tile[32][33];
  const int zi = blockIdx.z;
  const float* src = (zi == 0) ? Wq : (zi == 1) ? Wk : (zi == 2) ? Wv : Wp;
  unsigned short* dst = (zi == 3) ? wpT : wqkvT + (size_t)zi * 1048576;
  const int bx = blockIdx.x * 32, by = blockIdx.y * 32;
  const int tx = threadIdx.x & 31, ty = threadIdx.x >> 5;  // 32 x 8
  #pragma unroll
  for (int i = 0; i < 32; i += 8)
    tile[ty + i][tx] = src[(size_t)(by + ty + i) * 1024 + bx + tx];
  __syncthreads();
  #pragma unroll
  for (int i = 0; i < 32; i += 8)
    dst[(size_t)(bx + ty + i) * 1024 + by + tx] = f2bf(tile[tx][ty + i]);
}

// ---------------- GEMM: C[M,N] = A[M,K] @ BT[N,K]^T ----------------
// 3 LDS buffers, depth-1 staging, ONE barrier per K-step: iter t computes
// buf[t%3], stages buf[(t+1)%3]. A stage into buf[t%3] recurs at iter t+2,
// gated by barrier t+2 which all waves reach only after their buf[t%3] reads
// retired (lgkmcnt(0) before loop-back). vmcnt(4) leaves next-tile loads in
// flight across the barrier. qscale applied to bf16 cols < scale_cols;
// cols >= 2048 (V part) written TRANSPOSED into vTo when vTo != null.
__global__ __launch_bounds__(256) void gemm_bt(
    const unsigned short* __restrict__ A, const unsigned short* __restrict__ BT,
    unsigned short* __restrict__ Cb, float* __restrict__ Cf,
    const float* __restrict__ bias, int M, int N, int K,
    float qscale, int scale_cols, unsigned short* __restrict__ vTo) {
  __shared__ unsigned short As[3][4096];
  __shared__ unsigned short Bs[3][4096];
  const int tid = threadIdx.x;
  const int lane = tid & 63, w = tid >> 6;
  const int wr = w >> 1, wc = w & 1;
  const int brow = blockIdx.y << 7, bcol = blockIdx.x << 7;

  f32x4 z = {0.f, 0.f, 0.f, 0.f};
  f32x4 acc[4][4];
  #pragma unroll
  for (int m = 0; m < 4; ++m)
    #pragma unroll
    for (int n = 0; n < 4; ++n) acc[m][n] = z;

  const int srow = tid >> 2;
  const int scol = (tid & 3) << 3;
  const unsigned short* Ap = A + (size_t)(brow + srow) * K + scol;
  const unsigned short* Bp = BT + (size_t)(bcol + srow) * K + scol;
  const size_t rowK64 = (size_t)64 * K;

  #define GSTAGE(k0_, bi_)                                   \
    do {                                                     \
      unsigned short* AsW = &As[bi_][w * 512];               \
      unsigned short* BsW = &Bs[bi_][w * 512];               \
      gload16(Ap + (k0_), AsW);                              \
      gload16(Ap + rowK64 + (k0_), AsW + 2048);              \
      gload16(Bp + (k0_), BsW);                              \
      gload16(Bp + rowK64 + (k0_), BsW + 2048);              \
    } while (0)

  const int koff = (lane >> 4) << 3;
  const int ar = (wr << 6) + (lane & 15);
  const int br = (wc << 6) + (lane & 15);
  const int nt = K >> 5;
  int cur = 0;
  GSTAGE(0, 0);
  for (int t = 0; t < nt; ++t) {
    const int nxt = (cur + 1 == 3) ? 0 : cur + 1;
    if (t + 1 < nt) {
      GSTAGE((size_t)(t + 1) << 5, nxt);
      asm volatile("s_waitcnt vmcnt(4)" ::: "memory");  // tile t landed; t+1 in flight
    } else {
      asm volatile("s_waitcnt vmcnt(0)" ::: "memory");
    }
    __builtin_amdgcn_sched_barrier(0);
    __builtin_amdgcn_s_barrier();
    __builtin_amdgcn_sched_barrier(0);
    shortx8 af[4], bf[4];
    #pragma unroll
    for (int m = 0; m < 4; ++m) af[m] = *(const shortx8*)&As[cur][(ar + m * 16) * 32 + koff];
    #pragma unroll
    for (int n = 0; n < 4; ++n) bf[n] = *(const shortx8*)&Bs[cur][(br + n * 16) * 32 + koff];
    #pragma unroll
    for (int m = 0; m < 4; ++m)
      #pragma unroll
      for (int n = 0; n < 4; ++n) acc[m][n] = MFMA16(af[m], bf[n], acc[m][n]);
    asm volatile("s_waitcnt lgkmcnt(0)" ::: "memory");  // reads retired before next barrier
    __builtin_amdgcn_sched_barrier(0);
    cur = nxt;
  }
  #undef GSTAGE

  const int r0 = (lane >> 4) << 2;
  const int c0 = lane & 15;
  if (Cb) {
    if (vTo && bcol >= 2048) {
      #pragma unroll
      for (int m = 0; m < 4; ++m)
        #pragma unroll
        for (int n = 0; n < 4; ++n) {
          const int dp = bcol - 2048 + (wc << 6) + n * 16 + c0;
          const size_t rowb = brow + (wr << 6) + m * 16 + r0;
          uint2 u;
          u.x = cvtpk(acc[m][n][0], acc[m][n][1]);
          u.y = cvtpk(acc[m][n][2], acc[m][n][3]);
          *(uint2*)&vTo[(size_t)dp * 4096 + rowb] = u;
        }
    } else {
      #pragma unroll
      for (int m = 0; m < 4; ++m)
        #pragma unroll
        for (int n = 0; n < 4; ++n)
          #pragma unroll
          for (int j = 0; j < 4; ++j) {
            const size_t row = brow + (wr << 6) + m * 16 + r0 + j;
            const size_t col = bcol + (wc << 6) + n * 16 + c0;
            float v = acc[m][n][j];
            if ((int)col < scale_cols) v *= qscale;
            Cb[row * N + col] = f2bf(v);
          }
    }
  } else {
    #pragma unroll
    for (int m = 0; m < 4; ++m)
      #pragma unroll
      for (int n = 0; n < 4; ++n)
        #pragma unroll
        for (int j = 0; j < 4; ++j) {
          const size_t row = brow + (wr << 6) + m * 16 + r0 + j;
          const size_t col = bcol + (wc << 6) + n * 16 + c0;
          Cf[row * N + col] = acc[m][n][j] + bias[col];
        }
  }
}

// ---------------- flash attention v13 (kv-split, split waits, max3) ----------------
// Block = 4 INDEPENDENT warps over the same 32 q-rows; warp p does kv tiles
// t === p (mod 4), KVBLK=32. Single 8KB LDS buffer per warp. STAGE orders
// 4 K-loads then 4 V-loads so vmcnt(4) releases K early: read kf -> QK MFMA
// issues while V loads land -> vmcnt(0) -> read vf -> restage -> softmax+PV.
// QK^T swapped at 32x32x16; per-lane softmax (max3 tree + 1 permlane);
// P relayout in-register (cvt_pk + permlane32_swap); O^T accum; tree merge.

__global__ __launch_bounds__(256, 4) void attn_fwd(
    const unsigned short* __restrict__ qkv, const unsigned short* __restrict__ vT,
    unsigned short* __restrict__ att) {
  __shared__ unsigned short sh[4][4096];  // [warp][ K[32kv][64d] | V^T[64d][32kv] ]

  const int tid = threadIdx.x;
  const int lane = tid & 63;
  const int p = tid >> 6;                  // warp id = kv residue (mod 4)
  const int stream = blockIdx.x;           // (h,b)
  const int h = stream & 15, b = stream >> 4;
  const int qb = 63 - (int)blockIdx.y;     // 32-row q tile, descending work
  const int ql = lane & 31;
  const int hi = lane >> 5;
  const int q = qb * 32 + ql;

  // Q^T B-operand: qf[kc] = Q[q][16kc + 8hi + e], pre-scaled by SC_L2E
  shortx8 qf[4];
  {
    const unsigned short* qp = qkv + ((size_t)(b * 2048 + q)) * 3072 + h * 64 + 8 * hi;
    #pragma unroll
    for (int kc = 0; kc < 4; ++kc) qf[kc] = *(const shortx8*)(qp + 16 * kc);
  }

  f32x16 z16;
  #pragma unroll
  for (int i = 0; i < 16; ++i) z16[i] = 0.f;
  f32x16 accO0 = z16, accO1 = z16;  // O^T[d = 32dh + crow(r,hi)][q]
  float m_run = -__builtin_inff(), l_run = 0.f;

  // staging source bases (pre-swizzled): K row r -> chunk XOR S8(r), V -> S4(r)
  const unsigned short* kb[4];
  const unsigned short* vb[4];
  #pragma unroll
  for (int i = 0; i < 4; ++i) {
    const int krow = 8 * i + (lane >> 3);
    const int kcl = (lane & 7) ^ (((krow >> 1) ^ (krow >> 4)) & 7);
    kb[i] = qkv + ((size_t)(b * 2048 + krow)) * 3072 + 1024 + h * 64 + 8 * kcl;
    const int vrow = 16 * i + (lane >> 2);
    const int vcl = (lane & 3) ^ (((vrow >> 1) ^ (vrow >> 3)) & 3);
    vb[i] = vT + ((size_t)(h * 64 + vrow)) * 4096 + b * 2048 + 8 * vcl;
  }
  const int rs8 = ((ql >> 1) ^ (ql >> 4)) & 7;
  const int rs4 = ((ql >> 1) ^ (ql >> 3)) & 3;

  unsigned short* Kl = &sh[p][0];
  unsigned short* Vl = &sh[p][2048];

  // K loads first, V loads second: vmcnt(4) == K landed
  #define STAGE(t_)                                                        \
    do {                                                                   \
      _Pragma("unroll")                                                    \
      for (int i = 0; i < 4; ++i)                                          \
        gload16(kb[i] + (size_t)(t_) * 32 * 3072, Kl + i * 512);           \
      _Pragma("unroll")                                                    \
      for (int i = 0; i < 4; ++i)                                          \
        gload16(vb[i] + (t_) * 32, Vl + i * 512);                          \
    } while (0)

  if (p <= qb) STAGE(p);
  for (int t = p; t <= qb; t += 4) {
    asm volatile("s_waitcnt vmcnt(4)" ::: "memory");  // K tile landed
    __builtin_amdgcn_sched_barrier(0);
    shortx8 kf[4];
    #pragma unroll
    for (int kc = 0; kc < 4; ++kc)
      kf[kc] = *(const shortx8*)&Kl[ql * 64 + 8 * ((2 * kc + hi) ^ rs8)];
    asm volatile("s_waitcnt lgkmcnt(0)" ::: "memory");
    __builtin_amdgcn_sched_barrier(0);

    // QK^T issues while V loads finish
    __builtin_amdgcn_s_setprio(1);
    f32x16 s = z16;
    #pragma unroll
    for (int kc = 0; kc < 4; ++kc) s = MFMA32(kf[kc], qf[kc], s);
    __builtin_amdgcn_s_setprio(0);

    asm volatile("s_waitcnt vmcnt(0)" ::: "memory");  // V tile landed
    __builtin_amdgcn_sched_barrier(0);
    shortx8 vf[2][2];
    #pragma unroll
    for (int dh = 0; dh < 2; ++dh)
      #pragma unroll
      for (int ks = 0; ks < 2; ++ks)
        vf[dh][ks] = *(const shortx8*)&Vl[(32 * dh + ql) * 32 + 8 * ((2 * ks + hi) ^ rs4)];
    asm volatile("s_waitcnt lgkmcnt(0)" ::: "memory");  // frags in regs; buffer dead
    __builtin_amdgcn_sched_barrier(0);

    if (t + 4 <= qb) STAGE(t + 4);  // restage same buffer; compute hides return

    // causal mask on diagonal tile: kv_local = (r&3)+8(r>>2)+4hi, qrel = ql
    if (t == qb) {
      #pragma unroll
      for (int r = 0; r < 16; ++r) {
        const int kvl = (r & 3) + 8 * (r >> 2) + 4 * hi;
        if (kvl > ql) s[r] = -__builtin_inff();
      }
    }

    // per-lane max via v_max3 tree (8 insts) + partner exchange
    float t0 = max3(s[0], s[1], s[2]);
    float t1 = max3(s[3], s[4], s[5]);
    float t2 = max3(s[6], s[7], s[8]);
    float t3 = max3(s[9], s[10], s[11]);
    float t4 = max3(s[12], s[13], s[14]);
    float mx = fmaxf(max3(t0, t1, t2), max3(t3, t4, s[15]));
    mx = fmaxf(mx, partner32(mx, hi));

    if (!__all(mx <= m_run + 8.0f)) {  // defer-max (THR=8 in log2)
      const float nm = fmaxf(m_run, mx);
      const float alpha = fexp2(m_run - nm);
      l_run *= alpha;
      #pragma unroll
      for (int r = 0; r < 16; ++r) { accO0[r] *= alpha; accO1[r] *= alpha; }
      m_run = nm;
    }

    #pragma unroll
    for (int r = 0; r < 16; ++r) s[r] = fexp2(s[r] - m_run);
    float a8[8], a4[4];
    #pragma unroll
    for (int i = 0; i < 8; ++i) a8[i] = s[2 * i] + s[2 * i + 1];
    #pragma unroll
    for (int i = 0; i < 4; ++i) a4[i] = a8[2 * i] + a8[2 * i + 1];
    float rsum = (a4[0] + a4[1]) + (a4[2] + a4[3]);
    rsum += partner32(rsum, hi);
    l_run += rsum;

    // pack P + permlane exchange + PV
    unsigned wv[8];
    #pragma unroll
    for (int i = 0; i < 8; ++i) wv[i] = cvtpk(s[2 * i], s[2 * i + 1]);
    __builtin_amdgcn_s_setprio(1);
    #pragma unroll
    for (int ss = 0; ss < 2; ++ss) {
      uintx2 r02 = plswap(wv[4 * ss], wv[4 * ss + 2]);
      uintx2 r13 = plswap(wv[4 * ss + 1], wv[4 * ss + 3]);
      union { unsigned u[4]; shortx8 s8; } pb;
      pb.u[0] = r02[0];
      pb.u[1] = r13[0];
      pb.u[2] = r02[1];
      pb.u[3] = r13[1];
      accO0 = MFMA32(vf[0][ss], pb.s8, accO0);
      accO1 = MFMA32(vf[1][ss], pb.s8, accO1);
    }
    __builtin_amdgcn_s_setprio(0);
  }
  #undef STAGE

  // ---- 2-stage tree merge of 4 kv-partial states ----
  float* fb = (float*)&sh[0][0];
  #define DUMP(slot_)                                                          \
    do {                                                                       \
      float* ob = fb + (slot_) * 2048;                                         \
      _Pragma("unroll")                                                        \
      for (int rg = 0; rg < 4; ++rg) {                                         \
        f32x4 v0 = {accO0[4 * rg], accO0[4 * rg + 1],                          \
                    accO0[4 * rg + 2], accO0[4 * rg + 3]};                     \
        f32x4 v1 = {accO1[4 * rg], accO1[4 * rg + 1],                          \
                    accO1[4 * rg + 2], accO1[4 * rg + 3]};                     \
        *(f32x4*)&ob[(rg * 64 + lane) * 4] = v0;                               \
        *(f32x4*)&ob[((4 + rg) * 64 + lane) * 4] = v1;                         \
      }                                                                        \
      fb[4096 + (slot_) * 128 + lane] = m_run;                                 \
      fb[4096 + (slot_) * 128 + 64 + lane] = l_run;                            \
    } while (0)
  #define MERGE(slot_)                                                         \
    do {                                                                       \
      const float m2 = fb[4096 + (slot_) * 128 + lane];                        \
      const float l2 = fb[4096 + (slot_) * 128 + 64 + lane];                   \
      if (m2 != -__builtin_inff()) {                                           \
        float* ob = fb + (slot_) * 2048;                                       \
        const float mf = fmaxf(m_run, m2);                                     \
        const float a1 = fexp2(m_run - mf);                                    \
        const float a2 = fexp2(m2 - mf);                                       \
        _Pragma("unroll")                                                      \
        for (int rg = 0; rg < 4; ++rg) {                                       \
          f32x4 p0 = *(const f32x4*)&ob[(rg * 64 + lane) * 4];                 \
          f32x4 p1 = *(const f32x4*)&ob[((4 + rg) * 64 + lane) * 4];           \
          _Pragma("unroll")                                                    \
          for (int j = 0; j < 4; ++j) {                                        \
            accO0[4 * rg + j] = accO0[4 * rg + j] * a1 + p0[j] * a2;           \
            accO1[4 * rg + j] = accO1[4 * rg + j] * a1 + p1[j] * a2;           \
          }                                                                    \
        }                                                                      \
        l_run = l_run * a1 + l2 * a2;                                          \
        m_run = mf;                                                            \
      }                                                                        \
    } while (0)

  __syncthreads();
  if (p == 1) DUMP(0);
  if (p == 3) DUMP(1);
  __syncthreads();
  if (p == 0) MERGE(0);
  if (p == 2) MERGE(1);
  __syncthreads();
  if (p == 2) DUMP(0);
  __syncthreads();
  if (p == 0) {
    MERGE(0);
    const float inv = 1.f / l_run;
    unsigned short* op = att + ((size_t)(b * 2048 + q)) * 1024 + h * 64;
    #pragma unroll
    for (int rq = 0; rq < 4; ++rq) {
      shortx4 o0, o1;
      #pragma unroll
      for (int j = 0; j < 4; ++j) {
        o0[j] = (short)f2bf(accO0[4 * rq + j] * inv);
        o1[j] = (short)f2bf(accO1[4 * rq + j] * inv);
      }
      *(shortx4*)&op[8 * rq + 4 * hi] = o0;
      *(shortx4*)&op[32 + 8 * rq + 4 * hi] = o1;
    }
  }
  #undef DUMP
  #undef MERGE
}

// ---------------- launch ----------------
extern "C" void kernel_launch(void* const* d_in, const int* in_sizes, int n_in,
                              void* d_out, int out_size, void* d_ws, size_t ws_size,
                              hipStream_t stream) {
  const float* x  = (const float*)d_in[0];
  const float* Wq = (const float*)d_in[1];
  const float* Wk = (const float*)d_in[2];
  const float* Wv = (const float*)d_in[3];
  const float* Wp = (const float*)d_in[4];
  const float* bp = (const float*)d_in[5];

  char* ws = (char*)d_ws;
  unsigned short* xb    = (unsigned short*)(ws);                        //  8 MB [4096][1024]
  unsigned short* wqkvT = (unsigned short*)(ws + (size_t)8  * 1048576); //  6 MB [3072][1024]
  unsigned short* wpT   = (unsigned short*)(ws + (size_t)14 * 1048576); //  2 MB [1024][1024]
  unsigned short* qkv   = (unsigned short*)(ws + (size_t)16 * 1048576); // 24 MB [4096][3072]
  unsigned short* vT    = (unsigned short*)(ws + (size_t)40 * 1048576); //  8 MB [1024][4096]
  unsigned short* att   = (unsigned short*)(ws + (size_t)48 * 1048576); //  8 MB [4096][1024]

  cvt_x<<<dim3(4096), dim3(256), 0, stream>>>(x, xb, 1048576);
  transpose_w4<<<dim3(32, 32, 4), dim3(256), 0, stream>>>(Wq, Wk, Wv, Wp, wqkvT, wpT);
  gemm_bt<<<dim3(24, 32), dim3(256), 0, stream>>>(xb, wqkvT, qkv, nullptr, nullptr,
                                                  4096, 3072, 1024, SC_L2E, 1024, vT);
  attn_fwd<<<dim3(32, 64), dim3(256), 0, stream>>>(qkv, vT, att);
  gemm_bt<<<dim3(8, 32), dim3(256), 0, stream>>>(att, wpT, nullptr, (float*)d_out, bp,
                                                 4096, 1024, 1024, 0.f, 0, nullptr);
}